// Round 22
// baseline (74.687 us; speedup 1.0000x reference)
//
#include <hip/hip_runtime.h>
#include <math.h>

#define MM 16
#define CC 345
#define MC (MM*CC)   // 5520
#define KTOP 4
// Guard threshold in tc-space (validated R15/R20/R21: absmax unchanged, ~0.5% trigger).
#define GAP_THR 3e-7f
#define NT 512

__device__ __forceinline__ float fexp(float x) { return __expf(x); }
__device__ __forceinline__ float flog(float x) { return __logf(x); }

// width-16 reductions over a 16-lane group
__device__ __forceinline__ float rmax16(float v) {
    #pragma unroll
    for (int off = 8; off; off >>= 1) v = fmaxf(v, __shfl_xor(v, off, 16));
    return v;
}
__device__ __forceinline__ float rmin16(float v) {
    #pragma unroll
    for (int off = 8; off; off >>= 1) v = fminf(v, __shfl_xor(v, off, 16));
    return v;
}
__device__ __forceinline__ float rsum16(float v) {
    #pragma unroll
    for (int off = 8; off; off >>= 1) v += __shfl_xor(v, off, 16);
    return v;
}
// width-32 reductions over a 32-lane group
__device__ __forceinline__ float rmax32(float v) {
    #pragma unroll
    for (int off = 16; off; off >>= 1) v = fmaxf(v, __shfl_xor(v, off, 32));
    return v;
}
__device__ __forceinline__ float rsum32(float v) {
    #pragma unroll
    for (int off = 16; off; off >>= 1) v += __shfl_xor(v, off, 32);
    return v;
}

// One block per batch row b. 512 threads = 8 waves. 4 barriers.
__global__ __launch_bounds__(NT)
void ens_main(const float* __restrict__ y, const int* __restrict__ labels,
              float* __restrict__ out, float* __restrict__ partial, int B)
{
    const int b   = blockIdx.x;
    const int tid = threadIdx.x;

    __shared__ float sl[MC + 64];     // logits tile (+pad)
    __shared__ float sems[CC];        // ems_out (only sems[label] consumed)
    __shared__ float s_truep[MM], s_epl[MM], s_mx[MM];
    __shared__ float s_w[MM], s_pw[MM];
    __shared__ float s_red[NT/64];

    const int label = labels[b];
    const float* yb = y + (size_t)b * MC;

    // ---- Phase 1 (R20-verbatim): global -> LDS, vectorized float4
    {
        const float4* src = reinterpret_cast<const float4*>(yb);
        float4* dst = reinterpret_cast<float4*>(sl);
        for (int i = tid; i < MC/4; i += NT) dst[i] = src[i];
    }
    __syncthreads();   // #1

    // ---- Phase 2 (R20-verbatim): per-m softmax stats, 32 lanes per m,
    // register-cached from LDS. mx order-independent -> bit-exact.
    {
        const int m = tid >> 5;
        const int l = tid & 31;
        const float* row = sl + m * CC;
        float v[11];
        float mx = -INFINITY;
        #pragma unroll
        for (int k = 0; k < 11; ++k) {
            const int c = l + (k << 5);
            if (c < CC) { v[k] = row[c]; mx = fmaxf(mx, v[k]); }
            else          v[k] = 0.f;
        }
        mx = rmax32(mx);
        float se = 0.f;
        #pragma unroll
        for (int k = 0; k < 11; ++k) {
            const int c = l + (k << 5);
            if (c < CC) se += fexp(v[k] - mx);
        }
        se = rsum32(se);
        if (l == 0) {
            const float lt = row[label];
            s_mx[m]    = mx;                          // exact max, reused by 3b
            s_truep[m] = fexp(lt - mx) / se;          // fast probs[b,m,label]
            s_epl[m]   = -(lt - mx - flog(se));       // -log_softmax[b,m,label]
        }
    }
    __syncthreads();   // #2 — stats ready

    // ---- Phase 3 (R21-verbatim, verified bit-exact): entirely on wave 0.
    // 4 redundant 16-lane groups, in-wave bit-exact guard, no internal barriers.
    if (tid < 64) {
        const int l  = tid;
        const int lm = l & 15;
        const int mq = l >> 4;
        const int g  = l & 15;

        const float tpv  = s_truep[lm];
        const float eplv = s_epl[lm];

        // 3a: fast per-b math + top-4 by rank
        const float mxs = rmax16(tpv);
        const float e0  = fexp(tpv - mxs);
        const float tc  = e0 / rsum16(e0);                 // true_confs (fast)
        const float s1  = fmaxf(rsum16(fabsf(tc)), 1e-12f);
        const float wm  = tc / s1;                         // weighted_mat
        int rank = 0;
        #pragma unroll
        for (int j = 0; j < MM; ++j) {
            const float vj = __shfl(tc, j, 16);
            rank += (vj > tc) || (vj == tc && j < lm);
        }
        bool sel = (rank < KTOP);
        const float val4 = rmin16(sel ? tc : INFINITY);    // smallest selected
        const float val5 = rmax16(sel ? -INFINITY : tc);   // largest unselected
        const bool need = (val4 - val5 < GAP_THR);         // wave-uniform, rare

        // 3b: BIT-EXACT round-1 chain — libm expf, strided-16 ascending
        // global reads + xor-tree rsum16 (same exact mx), serial ascending
        // denominator, tie-ranked top-4.
        if (need) {
            float tpp4[4];
            #pragma unroll
            for (int i = 0; i < 4; ++i) {
                const int m = i * 4 + mq;
                const float* row = yb + m * CC;
                const float mx = s_mx[m];                  // bitwise phase-2 mx
                float se = 0.f;
                for (int c = g; c < CC; c += 16) se += expf(row[c] - mx);
                se = rsum16(se);
                tpp4[i] = expf(row[label] - mx) / se;
            }
            float tppv = 0.f;
            {
                const int src = (lm & 3) << 4;
                #pragma unroll
                for (int i = 0; i < 4; ++i) {
                    const float a_ = __shfl(tpp4[i], src, 64);
                    if ((lm >> 2) == i) tppv = a_;
                }
            }
            const float mxx = rmax16(tppv);
            const float ev  = expf(tppv - mxx);
            float ses = 0.f;
            #pragma unroll
            for (int m = 0; m < MM; ++m) ses += __shfl(ev, m, 16); // ascending
            const float tcpv = ev / ses;
            int rk = 0;
            #pragma unroll
            for (int j = 0; j < MM; ++j) {
                const float vj = __shfl(tcpv, j, 16);
                rk += (vj > tcpv) || (vj == tcpv && j < lm);
            }
            sel = (rk < KTOP);
        }

        // 3c: finish per-b math, publish weights
        const float post = sel ? tc : 0.f;
        const float psum = fmaxf(rsum16(fabsf(post)), 1e-12f);
        const float pw   = post / psum;
        const float mw = rmax16(wm);
        const float ex = fexp(wm - mw);
        const float xv = ex / rsum16(ex);
        const float mt = rmax16(tc);
        const float et = fexp(tc - mt);
        const float tv = et / rsum16(et);
        const float childp = eplv * xv;
        const float confp  = fmaxf(xv, 0.f) - xv * tv + flog(1.f + fexp(-fabsf(xv)));
        const float childs = rsum16(childp);
        const float confs  = rsum16(confp);
        if (l == 0) {
            partial[(size_t)b * 3 + 0] = childs;
            partial[(size_t)b * 3 + 1] = confs;
        }
        if (l < MM) {
            const size_t off_wm = (size_t)B * CC + 3;
            const size_t off_tc = off_wm + (size_t)B * MM;
            out[off_wm + (size_t)b * MM + l] = xv;  // wm_soft
            out[off_tc + (size_t)b * MM + l] = tc;  // true_confs
            s_w[l]  = wm;
            s_pw[l] = pw;
        }
    }
    __syncthreads();   // #3 — weights ready

    // ---- Phase 4+5 fused (R20-verbatim): ems_out / ems_out_post, then
    // ensemble loss via UNSHIFTED log-sum-exp (|ems| <~ 6, overflow-safe).
    {
        const int c = tid;
        const bool act = (c < CC);
        float a = 0.f;
        if (act) {
            float aa = 0.f, ap = 0.f;
            #pragma unroll
            for (int m = 0; m < MM; ++m) {
                const float vv = sl[m * CC + c];
                aa = fmaf(vv, s_w[m],  aa);
                ap = fmaf(vv, s_pw[m], ap);
            }
            sems[c] = aa;                      // only sems[label] consumed
            out[(size_t)b * CC + c] = ap;      // ems_out_post
            a = aa;
        }
        float e = act ? fexp(a) : 0.f;
        #pragma unroll
        for (int off = 32; off; off >>= 1) e += __shfl_xor(e, off);
        if ((tid & 63) == 0) s_red[tid >> 6] = e;
        __syncthreads();   // #4 — covers sems writes + s_red
        if (tid == 0) {
            float s = 0.f;
            #pragma unroll
            for (int w = 0; w < NT/64; ++w) s += s_red[w];
            partial[(size_t)b * 3 + 2] = -(sems[label] - flog(s));
        }
    }
}

// Two-stage deterministic reduction of per-b partials -> the 3 scalar losses.
__global__ __launch_bounds__(64)
void ens_reduce1(const float* __restrict__ partial, double* __restrict__ ws2, int B)
{
    const int t  = threadIdx.x;     // 0..63
    const int i  = blockIdx.x;      // 0..63
    const int r0 = i * 128 + t * 2; // 128 rows per block
    double c = 0.0, f = 0.0, e = 0.0;
    #pragma unroll
    for (int k = 0; k < 2; ++k) {
        const int r = r0 + k;
        c += (double)partial[(size_t)r * 3 + 0];
        f += (double)partial[(size_t)r * 3 + 1];
        e += (double)partial[(size_t)r * 3 + 2];
    }
    #pragma unroll
    for (int off = 32; off; off >>= 1) {
        c += __shfl_xor(c, off);
        f += __shfl_xor(f, off);
        e += __shfl_xor(e, off);
    }
    if (t == 0) {
        ws2[(size_t)i * 3 + 0] = c;
        ws2[(size_t)i * 3 + 1] = f;
        ws2[(size_t)i * 3 + 2] = e;
    }
}

__global__ __launch_bounds__(64)
void ens_reduce2(const double* __restrict__ ws2, float* __restrict__ out, int B)
{
    const int t = threadIdx.x;
    double c = ws2[(size_t)t * 3 + 0];
    double f = ws2[(size_t)t * 3 + 1];
    double e = ws2[(size_t)t * 3 + 2];
    #pragma unroll
    for (int off = 32; off; off >>= 1) {
        c += __shfl_xor(c, off);
        f += __shfl_xor(f, off);
        e += __shfl_xor(e, off);
    }
    if (t == 0) {
        const size_t base = (size_t)B * CC;
        out[base + 0] = (float)(c / (double)((size_t)B * MM));  // child_loss
        out[base + 1] = (float)(f / (double)((size_t)B * MM));  // confidence_loss
        out[base + 2] = (float)(e / (double)B);                 // ensemble_loss
    }
}

extern "C" void kernel_launch(void* const* d_in, const int* in_sizes, int n_in,
                              void* d_out, int out_size, void* d_ws, size_t ws_size,
                              hipStream_t stream)
{
    const float* y      = (const float*)d_in[0];
    const int*   labels = (const int*)d_in[1];
    const int    B      = in_sizes[1];      // 8192
    float* out     = (float*)d_out;
    float* partial = (float*)d_ws;          // B*3 floats
    double* ws2    = (double*)((char*)d_ws + (((size_t)B * 3 * sizeof(float) + 255) & ~(size_t)255));

    ens_main<<<dim3(B), dim3(NT), 0, stream>>>(y, labels, out, partial, B);
    ens_reduce1<<<dim3(64), dim3(64), 0, stream>>>(partial, ws2, B);
    ens_reduce2<<<dim3(1), dim3(64), 0, stream>>>(ws2, out, B);
}

// Round 23
// 63.148 us; speedup vs baseline: 1.1827x; 1.1827x over previous
//
#include <hip/hip_runtime.h>
#include <math.h>

#define MM 16
#define CC 345
#define MC (MM*CC)   // 5520
#define KTOP 4
// Guard threshold in tc-space (validated R15/R20: absmax unchanged, ~0.5% trigger).
#define GAP_THR 3e-7f
#define NT 512

__device__ __forceinline__ float fexp(float x) { return __expf(x); }
__device__ __forceinline__ float flog(float x) { return __logf(x); }

// width-16 reductions over a 16-lane group
__device__ __forceinline__ float rmax16(float v) {
    #pragma unroll
    for (int off = 8; off; off >>= 1) v = fmaxf(v, __shfl_xor(v, off, 16));
    return v;
}
__device__ __forceinline__ float rmin16(float v) {
    #pragma unroll
    for (int off = 8; off; off >>= 1) v = fminf(v, __shfl_xor(v, off, 16));
    return v;
}
__device__ __forceinline__ float rsum16(float v) {
    #pragma unroll
    for (int off = 8; off; off >>= 1) v += __shfl_xor(v, off, 16);
    return v;
}
// width-32 reductions over a 32-lane group
__device__ __forceinline__ float rmax32(float v) {
    #pragma unroll
    for (int off = 16; off; off >>= 1) v = fmaxf(v, __shfl_xor(v, off, 32));
    return v;
}
__device__ __forceinline__ float rsum32(float v) {
    #pragma unroll
    for (int off = 16; off; off >>= 1) v += __shfl_xor(v, off, 32);
    return v;
}

// One block per batch row b. 512 threads = 8 waves. 4 barriers (common path).
__global__ __launch_bounds__(NT)
void ens_main(const float* __restrict__ y, const int* __restrict__ labels,
              float* __restrict__ out, float* __restrict__ partial, int B)
{
    const int b   = blockIdx.x;
    const int tid = threadIdx.x;

    __shared__ float sl[MC + 64];     // logits tile (+pad)
    __shared__ float s_truep[MM], s_epl[MM], s_mx[MM], s_tpp[MM];
    __shared__ float s_w[MM], s_pw[MM];
    __shared__ float s_red[NT/64];
    __shared__ float s_lab;           // ems_out[label] (only value phase 5 needs)
    __shared__ int   s_need;
    __shared__ unsigned s_selmask;

    // ---- Phase 1 (R20-verbatim): global -> LDS, vectorized float4
    {
        const float4* src = reinterpret_cast<const float4*>(y + (size_t)b * MC);
        float4* dst = reinterpret_cast<float4*>(sl);
        for (int i = tid; i < MC/4; i += NT) dst[i] = src[i];
    }
    __syncthreads();   // #1

    const int label = labels[b];

    // ---- Phase 2 (R20-verbatim): per-m softmax stats, 32 lanes per m,
    // register-cached from LDS. mx order-independent -> bit-exact.
    {
        const int m = tid >> 5;
        const int l = tid & 31;
        const float* row = sl + m * CC;
        float v[11];
        float mx = -INFINITY;
        #pragma unroll
        for (int k = 0; k < 11; ++k) {
            const int c = l + (k << 5);
            if (c < CC) { v[k] = row[c]; mx = fmaxf(mx, v[k]); }
            else          v[k] = 0.f;
        }
        mx = rmax32(mx);
        float se = 0.f;
        #pragma unroll
        for (int k = 0; k < 11; ++k) {
            const int c = l + (k << 5);
            if (c < CC) se += fexp(v[k] - mx);
        }
        se = rsum32(se);
        if (l == 0) {
            const float lt = row[label];
            s_mx[m]    = mx;                          // exact max, reused by 3b
            s_truep[m] = fexp(lt - mx) / se;          // fast probs[b,m,label]
            s_epl[m]   = -(lt - mx - flog(se));       // -log_softmax[b,m,label]
        }
    }
    __syncthreads();   // #2 — stats ready

    // ---- Phase 3a + speculative 3c (lanes 0..15): everything except the
    // final pw is sel-INDEPENDENT, so compute and publish it all now; pw is
    // published speculatively from the fast selection and corrected in the
    // rare guarded path below.
    if (tid < MM) {
        const int l = tid;
        const size_t off_wm = (size_t)B * CC + 3;
        const size_t off_tc = off_wm + (size_t)B * MM;

        const float tp = s_truep[l];
        const float mx = rmax16(tp);
        const float e  = fexp(tp - mx);
        const float tc = e / rsum16(e);
        const float s1 = fmaxf(rsum16(fabsf(tc)), 1e-12f);
        const float wm = tc / s1;
        int rank = 0;
        #pragma unroll
        for (int j = 0; j < MM; ++j) {
            const float vj = __shfl(tc, j, 16);
            rank += (vj > tc) || (vj == tc && j < l);
        }
        const bool sel = (rank < KTOP);
        // Boundary-gap guard (see GAP_THR comment above)
        const float val4 = rmin16(sel ? tc : INFINITY);    // smallest selected
        const float val5 = rmax16(sel ? -INFINITY : tc);   // largest unselected
        if (l == 0) s_need = (val4 - val5 < GAP_THR) ? 1 : 0;

        // speculative pw from fast selection
        const float post = sel ? tc : 0.f;
        const float psum = fmaxf(rsum16(fabsf(post)), 1e-12f);
        s_pw[l] = post / psum;
        s_w[l]  = wm;

        // sel-independent finishers
        const float mw = rmax16(wm);
        const float ex = fexp(wm - mw);
        const float xv = ex / rsum16(ex);
        const float mt = rmax16(tc);
        const float et = fexp(tc - mt);
        const float tv = et / rsum16(et);
        const float childp = s_epl[l] * xv;
        const float confp  = fmaxf(xv, 0.f) - xv * tv + flog(1.f + fexp(-fabsf(xv)));
        const float childs = rsum16(childp);
        const float confs  = rsum16(confp);
        if (l == 0) {
            partial[(size_t)b * 3 + 0] = childs;
            partial[(size_t)b * 3 + 1] = confs;
        }
        out[off_wm + (size_t)b * MM + l] = xv;  // wm_soft
        out[off_tc + (size_t)b * MM + l] = tc;  // true_confs
    }
    __syncthreads();   // #3 — weights (speculative) + s_need ready

    // ---- Phase 3b (R20-verbatim internals, rare): BIT-EXACT round-1 chain;
    // corrects only s_pw. Block-uniform condition -> conditional barriers legal.
    if (s_need) {
        if (tid < 256) {
            const int m = tid >> 4;
            const int l = tid & 15;
            const float* row = sl + m * CC;
            const float mx = s_mx[m];
            float se = 0.f;
            for (int c = l; c < CC; c += 16) se += expf(row[c] - mx);
            se = rsum16(se);
            if (l == 0) s_tpp[m] = expf(row[label] - mx) / se;
        }
        __syncthreads();
        if (tid == 0) {
            float tcp[MM];
            float mxx = -INFINITY;
            for (int m = 0; m < MM; ++m) mxx = fmaxf(mxx, s_tpp[m]);
            float ses = 0.f;
            for (int m = 0; m < MM; ++m) { tcp[m] = expf(s_tpp[m] - mxx); ses += tcp[m]; }
            for (int m = 0; m < MM; ++m) tcp[m] /= ses;
            bool used[MM];
            for (int m = 0; m < MM; ++m) used[m] = false;
            unsigned msk = 0;
            for (int k = 0; k < KTOP; ++k) {
                int bi = -1; float bv = -INFINITY;
                for (int m = 0; m < MM; ++m)
                    if (!used[m] && tcp[m] > bv) { bv = tcp[m]; bi = m; }
                used[bi] = true; msk |= (1u << bi);
            }
            s_selmask = msk;
        }
        __syncthreads();
        if (tid < MM) {
            const int l = tid;
            // recompute tc exactly as in 3a (same inputs -> same bits)
            const float tp = s_truep[l];
            const float mx = rmax16(tp);
            const float e  = fexp(tp - mx);
            const float tc = e / rsum16(e);
            const bool sel2 = ((s_selmask >> l) & 1u) != 0;
            const float post = sel2 ? tc : 0.f;
            const float psum = fmaxf(rsum16(fabsf(post)), 1e-12f);
            s_pw[l] = post / psum;
        }
        __syncthreads();   // republish corrected pw
    }

    // ---- Phase 4+5 fused: ems_out / ems_out_post, then ensemble loss via
    // UNSHIFTED log-sum-exp (|ems| <~ 6, overflow-safe). Only ems[label] is
    // kept (single s_lab float instead of a 345-word LDS array).
    {
        const int c = tid;
        const bool act = (c < CC);
        float a = 0.f;
        if (act) {
            float aa = 0.f, ap = 0.f;
            #pragma unroll
            for (int m = 0; m < MM; ++m) {
                const float vv = sl[m * CC + c];
                aa = fmaf(vv, s_w[m],  aa);
                ap = fmaf(vv, s_pw[m], ap);
            }
            if (c == label) s_lab = aa;
            out[(size_t)b * CC + c] = ap;      // ems_out_post
            a = aa;
        }
        float e = act ? fexp(a) : 0.f;
        #pragma unroll
        for (int off = 32; off; off >>= 1) e += __shfl_xor(e, off);
        if ((tid & 63) == 0) s_red[tid >> 6] = e;
        __syncthreads();   // #4 — covers s_lab + s_red
        if (tid == 0) {
            float s = 0.f;
            #pragma unroll
            for (int w = 0; w < NT/64; ++w) s += s_red[w];
            partial[(size_t)b * 3 + 2] = -(s_lab - flog(s));
        }
    }
}

// Two-stage deterministic reduction of per-b partials -> the 3 scalar losses.
__global__ __launch_bounds__(64)
void ens_reduce1(const float* __restrict__ partial, double* __restrict__ ws2, int B)
{
    const int t  = threadIdx.x;     // 0..63
    const int i  = blockIdx.x;      // 0..63
    const int r0 = i * 128 + t * 2; // 128 rows per block
    double c = 0.0, f = 0.0, e = 0.0;
    #pragma unroll
    for (int k = 0; k < 2; ++k) {
        const int r = r0 + k;
        c += (double)partial[(size_t)r * 3 + 0];
        f += (double)partial[(size_t)r * 3 + 1];
        e += (double)partial[(size_t)r * 3 + 2];
    }
    #pragma unroll
    for (int off = 32; off; off >>= 1) {
        c += __shfl_xor(c, off);
        f += __shfl_xor(f, off);
        e += __shfl_xor(e, off);
    }
    if (t == 0) {
        ws2[(size_t)i * 3 + 0] = c;
        ws2[(size_t)i * 3 + 1] = f;
        ws2[(size_t)i * 3 + 2] = e;
    }
}

__global__ __launch_bounds__(64)
void ens_reduce2(const double* __restrict__ ws2, float* __restrict__ out, int B)
{
    const int t = threadIdx.x;
    double c = ws2[(size_t)t * 3 + 0];
    double f = ws2[(size_t)t * 3 + 1];
    double e = ws2[(size_t)t * 3 + 2];
    #pragma unroll
    for (int off = 32; off; off >>= 1) {
        c += __shfl_xor(c, off);
        f += __shfl_xor(f, off);
        e += __shfl_xor(e, off);
    }
    if (t == 0) {
        const size_t base = (size_t)B * CC;
        out[base + 0] = (float)(c / (double)((size_t)B * MM));  // child_loss
        out[base + 1] = (float)(f / (double)((size_t)B * MM));  // confidence_loss
        out[base + 2] = (float)(e / (double)B);                 // ensemble_loss
    }
}

extern "C" void kernel_launch(void* const* d_in, const int* in_sizes, int n_in,
                              void* d_out, int out_size, void* d_ws, size_t ws_size,
                              hipStream_t stream)
{
    const float* y      = (const float*)d_in[0];
    const int*   labels = (const int*)d_in[1];
    const int    B      = in_sizes[1];      // 8192
    float* out     = (float*)d_out;
    float* partial = (float*)d_ws;          // B*3 floats
    double* ws2    = (double*)((char*)d_ws + (((size_t)B * 3 * sizeof(float) + 255) & ~(size_t)255));

    ens_main<<<dim3(B), dim3(NT), 0, stream>>>(y, labels, out, partial, B);
    ens_reduce1<<<dim3(64), dim3(64), 0, stream>>>(partial, ws2, B);
    ens_reduce2<<<dim3(1), dim3(64), 0, stream>>>(ws2, out, B);
}

// Round 24
// 56.065 us; speedup vs baseline: 1.3322x; 1.1263x over previous
//
#include <hip/hip_runtime.h>
#include <math.h>

#define MM 16
#define CC 345
#define MC (MM*CC)   // 5520
#define KTOP 4
// Guard threshold in tc-space (validated R15/R20: absmax unchanged, ~0.5% trigger).
#define GAP_THR 3e-7f
#define NT 256       // 4 waves/block -> ~7 blocks/CU (vs 4 at NT=512)

__device__ __forceinline__ float fexp(float x) { return __expf(x); }
__device__ __forceinline__ float flog(float x) { return __logf(x); }

// width-16 reductions over a 16-lane group
__device__ __forceinline__ float rmax16(float v) {
    #pragma unroll
    for (int off = 8; off; off >>= 1) v = fmaxf(v, __shfl_xor(v, off, 16));
    return v;
}
__device__ __forceinline__ float rmin16(float v) {
    #pragma unroll
    for (int off = 8; off; off >>= 1) v = fminf(v, __shfl_xor(v, off, 16));
    return v;
}
__device__ __forceinline__ float rsum16(float v) {
    #pragma unroll
    for (int off = 8; off; off >>= 1) v += __shfl_xor(v, off, 16);
    return v;
}

// One block per batch row b. 256 threads = 4 waves. 4 barriers (common path).
__global__ __launch_bounds__(NT)
void ens_main(const float* __restrict__ y, const int* __restrict__ labels,
              float* __restrict__ out, float* __restrict__ partial, int B)
{
    const int b   = blockIdx.x;
    const int tid = threadIdx.x;

    __shared__ float sl[MC + 64];     // logits tile (+pad) ~22.3 KB
    __shared__ float s_truep[MM], s_epl[MM], s_mx[MM], s_tpp[MM];
    __shared__ float s_w[MM], s_pw[MM];
    __shared__ float s_red[NT/64];
    __shared__ float s_lab;           // ems_out[label]
    __shared__ int   s_need;
    __shared__ unsigned s_selmask;

    // ---- Phase 1: global -> LDS, vectorized float4 (5520 % 4 == 0)
    {
        const float4* src = reinterpret_cast<const float4*>(y + (size_t)b * MC);
        float4* dst = reinterpret_cast<float4*>(sl);
        for (int i = tid; i < MC/4; i += NT) dst[i] = src[i];
    }
    __syncthreads();   // #1

    const int label = labels[b];

    // ---- Phase 2: per-m softmax stats, 16 lanes per m (R5-passing pattern),
    // register-cached from LDS. mx order-independent -> bit-exact.
    {
        const int m = tid >> 4;
        const int l = tid & 15;
        const float* row = sl + m * CC;
        float v[22];
        float mx = -INFINITY;
        #pragma unroll
        for (int k = 0; k < 22; ++k) {
            const int c = l + (k << 4);
            if (c < CC) { v[k] = row[c]; mx = fmaxf(mx, v[k]); }
            else          v[k] = 0.f;
        }
        mx = rmax16(mx);
        float se = 0.f;
        #pragma unroll
        for (int k = 0; k < 22; ++k) {
            const int c = l + (k << 4);
            if (c < CC) se += fexp(v[k] - mx);
        }
        se = rsum16(se);
        if (l == 0) {
            const float lt = row[label];
            s_mx[m]    = mx;                          // exact max, reused by 3b
            s_truep[m] = fexp(lt - mx) / se;          // fast probs[b,m,label]
            s_epl[m]   = -(lt - mx - flog(se));       // -log_softmax[b,m,label]
        }
    }
    __syncthreads();   // #2 — stats ready

    // ---- Phase 3a + speculative 3c (lanes 0..15, R23-verbatim): everything
    // except pw is sel-independent; pw published speculatively, corrected by
    // the rare guarded path.
    if (tid < MM) {
        const int l = tid;
        const size_t off_wm = (size_t)B * CC + 3;
        const size_t off_tc = off_wm + (size_t)B * MM;

        const float tp = s_truep[l];
        const float mx = rmax16(tp);
        const float e  = fexp(tp - mx);
        const float tc = e / rsum16(e);
        const float s1 = fmaxf(rsum16(fabsf(tc)), 1e-12f);
        const float wm = tc / s1;
        int rank = 0;
        #pragma unroll
        for (int j = 0; j < MM; ++j) {
            const float vj = __shfl(tc, j, 16);
            rank += (vj > tc) || (vj == tc && j < l);
        }
        const bool sel = (rank < KTOP);
        const float val4 = rmin16(sel ? tc : INFINITY);    // smallest selected
        const float val5 = rmax16(sel ? -INFINITY : tc);   // largest unselected
        if (l == 0) s_need = (val4 - val5 < GAP_THR) ? 1 : 0;

        // speculative pw from fast selection
        const float post = sel ? tc : 0.f;
        const float psum = fmaxf(rsum16(fabsf(post)), 1e-12f);
        s_pw[l] = post / psum;
        s_w[l]  = wm;

        // sel-independent finishers
        const float mw = rmax16(wm);
        const float ex = fexp(wm - mw);
        const float xv = ex / rsum16(ex);
        const float mt = rmax16(tc);
        const float et = fexp(tc - mt);
        const float tv = et / rsum16(et);
        const float childp = s_epl[l] * xv;
        const float confp  = fmaxf(xv, 0.f) - xv * tv + flog(1.f + fexp(-fabsf(xv)));
        const float childs = rsum16(childp);
        const float confs  = rsum16(confp);
        if (l == 0) {
            partial[(size_t)b * 3 + 0] = childs;
            partial[(size_t)b * 3 + 1] = confs;
        }
        out[off_wm + (size_t)b * MM + l] = xv;  // wm_soft
        out[off_tc + (size_t)b * MM + l] = tc;  // true_confs
    }
    __syncthreads();   // #3 — weights (speculative) + s_need ready

    // ---- Phase 3b (R23-verbatim internals, rare): BIT-EXACT round-1 chain;
    // corrects only s_pw. Block-uniform condition -> conditional barriers legal.
    if (s_need) {
        {
            const int m = tid >> 4;
            const int l = tid & 15;
            const float* row = sl + m * CC;
            const float mx = s_mx[m];
            float se = 0.f;
            for (int c = l; c < CC; c += 16) se += expf(row[c] - mx);
            se = rsum16(se);
            if (l == 0) s_tpp[m] = expf(row[label] - mx) / se;
        }
        __syncthreads();
        if (tid == 0) {
            float tcp[MM];
            float mxx = -INFINITY;
            for (int m = 0; m < MM; ++m) mxx = fmaxf(mxx, s_tpp[m]);
            float ses = 0.f;
            for (int m = 0; m < MM; ++m) { tcp[m] = expf(s_tpp[m] - mxx); ses += tcp[m]; }
            for (int m = 0; m < MM; ++m) tcp[m] /= ses;
            bool used[MM];
            for (int m = 0; m < MM; ++m) used[m] = false;
            unsigned msk = 0;
            for (int k = 0; k < KTOP; ++k) {
                int bi = -1; float bv = -INFINITY;
                for (int m = 0; m < MM; ++m)
                    if (!used[m] && tcp[m] > bv) { bv = tcp[m]; bi = m; }
                used[bi] = true; msk |= (1u << bi);
            }
            s_selmask = msk;
        }
        __syncthreads();
        if (tid < MM) {
            const int l = tid;
            // recompute tc exactly as in 3a (same inputs -> same bits)
            const float tp = s_truep[l];
            const float mx = rmax16(tp);
            const float e  = fexp(tp - mx);
            const float tc = e / rsum16(e);
            const bool sel2 = ((s_selmask >> l) & 1u) != 0;
            const float post = sel2 ? tc : 0.f;
            const float psum = fmaxf(rsum16(fabsf(post)), 1e-12f);
            s_pw[l] = post / psum;
        }
        __syncthreads();   // republish corrected pw
    }

    // ---- Phase 4+5 fused: two columns per thread (c, c+256); ensemble loss
    // via UNSHIFTED log-sum-exp (|ems| <~ 6, overflow-safe); only ems[label]
    // kept (single s_lab float).
    {
        const int c0 = tid;            // always < 345
        const int c1 = tid + NT;
        const bool act1 = (c1 < CC);
        float a0 = 0.f, p0 = 0.f, a1 = 0.f, p1 = 0.f;
        #pragma unroll
        for (int m = 0; m < MM; ++m) {
            const float w_ = s_w[m];
            const float q_ = s_pw[m];
            const float v0 = sl[m * CC + c0];
            a0 = fmaf(v0, w_, a0);
            p0 = fmaf(v0, q_, p0);
            if (act1) {
                const float v1 = sl[m * CC + c1];
                a1 = fmaf(v1, w_, a1);
                p1 = fmaf(v1, q_, p1);
            }
        }
        if (c0 == label) s_lab = a0;
        if (act1 && c1 == label) s_lab = a1;
        out[(size_t)b * CC + c0] = p0;             // ems_out_post
        if (act1) out[(size_t)b * CC + c1] = p1;

        float e = fexp(a0) + (act1 ? fexp(a1) : 0.f);
        #pragma unroll
        for (int off = 32; off; off >>= 1) e += __shfl_xor(e, off);
        if ((tid & 63) == 0) s_red[tid >> 6] = e;
        __syncthreads();   // #4 — covers s_lab + s_red
        if (tid == 0) {
            float s = 0.f;
            #pragma unroll
            for (int w = 0; w < NT/64; ++w) s += s_red[w];
            partial[(size_t)b * 3 + 2] = -(s_lab - flog(s));
        }
    }
}

// Two-stage deterministic reduction of per-b partials -> the 3 scalar losses.
__global__ __launch_bounds__(64)
void ens_reduce1(const float* __restrict__ partial, double* __restrict__ ws2, int B)
{
    const int t  = threadIdx.x;     // 0..63
    const int i  = blockIdx.x;      // 0..63
    const int r0 = i * 128 + t * 2; // 128 rows per block
    double c = 0.0, f = 0.0, e = 0.0;
    #pragma unroll
    for (int k = 0; k < 2; ++k) {
        const int r = r0 + k;
        c += (double)partial[(size_t)r * 3 + 0];
        f += (double)partial[(size_t)r * 3 + 1];
        e += (double)partial[(size_t)r * 3 + 2];
    }
    #pragma unroll
    for (int off = 32; off; off >>= 1) {
        c += __shfl_xor(c, off);
        f += __shfl_xor(f, off);
        e += __shfl_xor(e, off);
    }
    if (t == 0) {
        ws2[(size_t)i * 3 + 0] = c;
        ws2[(size_t)i * 3 + 1] = f;
        ws2[(size_t)i * 3 + 2] = e;
    }
}

__global__ __launch_bounds__(64)
void ens_reduce2(const double* __restrict__ ws2, float* __restrict__ out, int B)
{
    const int t = threadIdx.x;
    double c = ws2[(size_t)t * 3 + 0];
    double f = ws2[(size_t)t * 3 + 1];
    double e = ws2[(size_t)t * 3 + 2];
    #pragma unroll
    for (int off = 32; off; off >>= 1) {
        c += __shfl_xor(c, off);
        f += __shfl_xor(f, off);
        e += __shfl_xor(e, off);
    }
    if (t == 0) {
        const size_t base = (size_t)B * CC;
        out[base + 0] = (float)(c / (double)((size_t)B * MM));  // child_loss
        out[base + 1] = (float)(f / (double)((size_t)B * MM));  // confidence_loss
        out[base + 2] = (float)(e / (double)B);                 // ensemble_loss
    }
}

extern "C" void kernel_launch(void* const* d_in, const int* in_sizes, int n_in,
                              void* d_out, int out_size, void* d_ws, size_t ws_size,
                              hipStream_t stream)
{
    const float* y      = (const float*)d_in[0];
    const int*   labels = (const int*)d_in[1];
    const int    B      = in_sizes[1];      // 8192
    float* out     = (float*)d_out;
    float* partial = (float*)d_ws;          // B*3 floats
    double* ws2    = (double*)((char*)d_ws + (((size_t)B * 3 * sizeof(float) + 255) & ~(size_t)255));

    ens_main<<<dim3(B), dim3(NT), 0, stream>>>(y, labels, out, partial, B);
    ens_reduce1<<<dim3(64), dim3(64), 0, stream>>>(partial, ws2, B);
    ens_reduce2<<<dim3(1), dim3(64), 0, stream>>>(ws2, out, B);
}